// Round 6
// baseline (312.482 us; speedup 1.0000x reference)
//
#include <hip/hip_runtime.h>
#include <hip/hip_bf16.h>

#define B_   32
#define C_   128
#define H_   56
#define W_   56
#define HW_  (H_*W_)
#define BHW_ (B_*HW_)        // 100352; 3136 = 196*16 (b-boundaries 16-aligned)
#define K5_  5
#define KK_  25
#define CR_  32
#define CE_  512
#define EPS_ 1e-6f

typedef __hip_bfloat16 bf16;
typedef __attribute__((ext_vector_type(8))) short short8;   // 8 bf16 (4 VGPRs)
typedef __attribute__((ext_vector_type(4))) float f32x4;

// ---------- workspace layout (bytes) ----------
// pooled fp32 [B*C]        @ 0         (16,384)
// dyn    fp32 [B*C*25]     @ 16,384    (409,600)
// gx2    fp32 [B*CE]       @ 425,984   (65,536)
// scale  fp32 [B*CE]       @ 491,520   (65,536)
// sb     fp32 [C]          @ 557,056   (512)
// weB    bf16 [CE*C]       @ 557,568   (131,072)
// yT     bf16 [BHW][C]     @ 819,712   (25,690,112)
//   sws bf16 [B][C][CE] (4,194,304 B) ALIASES head of yT (yT dead after expand)
// eT     bf16 [BHW][CE]    @ 26,509,824 (102,760,448)  (z aliases head of eT)

__device__ __forceinline__ float wave_reduce_sum(float v) {
#pragma unroll
  for (int off = 32; off > 0; off >>= 1) v += __shfl_down(v, off, 64);
  return v;
}
__device__ __forceinline__ float bf2f(unsigned short u) {
  return __uint_as_float(((unsigned)u) << 16);
}
__device__ __forceinline__ unsigned short f2bf_bits(float f) {
  bf16 h = __float2bfloat16(f);
  unsigned short u;
  __builtin_memcpy(&u, &h, 2);
  return u;
}
// sigmoid-form GELU: v * sigmoid(1.702 v)
__device__ __forceinline__ float fast_gelu(float v) {
  float t = __expf(-1.702f * v);
  return v * __builtin_amdgcn_rcpf(1.0f + t);
}

// ---------------- K0: weight bf16 conversion ----------------
__global__ __launch_bounds__(256) void prep_kernel(const float* __restrict__ we,
                                                   bf16* __restrict__ weB) {
  int i = blockIdx.x * 256 + threadIdx.x;
  if (i < CE_ * C_) weB[i] = __float2bfloat16(we[i]);
}

// ---------------- K1: global average pool ----------------
__global__ __launch_bounds__(256) void pool_kernel(const float* __restrict__ x,
                                                   float* __restrict__ pooled) {
  int bc = blockIdx.x;
  const float* xp = x + (size_t)bc * HW_;
  float s = 0.f;
  for (int i = threadIdx.x; i < HW_; i += 256) s += xp[i];
  s = wave_reduce_sum(s);
  __shared__ float red[4];
  int lane = threadIdx.x & 63, wid = threadIdx.x >> 6;
  if (lane == 0) red[wid] = s;
  __syncthreads();
  if (threadIdx.x == 0) pooled[bc] = (red[0] + red[1] + red[2] + red[3]) * (1.0f / HW_);
}

// ---------------- K2: fc1 -> LN1 -> fc2 (dyn weights) ----------------
__global__ __launch_bounds__(256) void fc_kernel(const float* __restrict__ pooled,
                                                 const float* __restrict__ w_fc1,
                                                 const float* __restrict__ ln1_w,
                                                 const float* __restrict__ ln1_b,
                                                 const float* __restrict__ w_fc2,
                                                 float* __restrict__ dyn) {
  int b = blockIdx.x;
  int tid = threadIdx.x;
  __shared__ float sp[C_];
  __shared__ float sh[CR_];
  __shared__ float shn[CR_];
  __shared__ float stats[2];
  if (tid < C_) sp[tid] = pooled[b * C_ + tid];
  __syncthreads();
  if (tid < CR_) {
    float acc = 0.f;
    const float* wr = w_fc1 + tid * C_;
#pragma unroll 4
    for (int c = 0; c < C_; ++c) acc += sp[c] * wr[c];
    sh[tid] = acc;
  }
  __syncthreads();
  if (tid == 0) {
    float u = 0.f;
    for (int j = 0; j < CR_; ++j) u += sh[j];
    u *= (1.0f / CR_);
    float v = 0.f;
    for (int j = 0; j < CR_; ++j) { float d = sh[j] - u; v += d * d; }
    v *= (1.0f / CR_);
    stats[0] = u;
    stats[1] = rsqrtf(v + EPS_);
  }
  __syncthreads();
  if (tid < CR_) shn[tid] = (sh[tid] - stats[0]) * stats[1] * ln1_w[tid] + ln1_b[tid];
  __syncthreads();
  for (int i = tid; i < C_ * KK_; i += 256) {
    const float* wr = w_fc2 + i * CR_;
    float acc = 0.f;
#pragma unroll
    for (int j = 0; j < CR_; ++j) acc += shn[j] * wr[j];
    dyn[b * (C_ * KK_) + i] = acc;
  }
}

// ---------------- K3a: dynamic depthwise 5x5 conv -> z (bf16, [b][c][hw]) ----------------
__global__ __launch_bounds__(256) void conv_kernel(const float* __restrict__ x,
                                                   const float* __restrict__ dyn,
                                                   bf16* __restrict__ z) {
  int bc = blockIdx.x;
  int b = bc >> 7;
  int c = bc & 127;
  int tid = threadIdx.x;
  __shared__ float xs[(H_ + 4) * 64];   // rows -2..57 at (r+2)*64; 15,360 B
  __shared__ float wks[KK_];
  {  // zero halo rows 0,1,58,59
    int r = tid >> 6;
    int rr = (r < 2) ? r : (56 + r);
    xs[rr * 64 + (tid & 63)] = 0.f;
  }
  if (tid < 224) {  // zero halo cols 0,1,58,59 of data rows
    int r = tid >> 2, q = tid & 3;
    int col = (q < 2) ? q : (56 + q);
    xs[(r + 2) * 64 + col] = 0.f;
  }
  if (tid < KK_) wks[tid] = dyn[b * (C_ * KK_) + c * KK_ + tid];
  const float4* xp4 = reinterpret_cast<const float4*>(x + (size_t)bc * HW_);
  for (int i = tid; i < 784; i += 256) {
    float4 v = xp4[i];
    int h = i / 14, w4 = (i % 14) * 4;
    float* dst = &xs[(h + 2) * 64 + 2 + w4];
    dst[0] = v.x; dst[1] = v.y; dst[2] = v.z; dst[3] = v.w;
  }
  __syncthreads();
  float wr[KK_];
#pragma unroll
  for (int j = 0; j < KK_; ++j) wr[j] = wks[j];
  for (int g = tid; g < 784; g += 256) {
    int h = g / 14;
    int w4 = (g % 14) * 4;
    float a0 = 0.f, a1 = 0.f, a2 = 0.f, a3 = 0.f;
#pragma unroll
    for (int dh = 0; dh < K5_; ++dh) {
      const float* row = &xs[(h + dh) * 64 + w4];
      float4 va = *reinterpret_cast<const float4*>(row);
      float4 vb = *reinterpret_cast<const float4*>(row + 4);
      float v0 = va.x, v1 = va.y, v2 = va.z, v3 = va.w;
      float v4 = vb.x, v5 = vb.y, v6 = vb.z, v7 = vb.w;
      float u0 = wr[dh * 5 + 0], u1 = wr[dh * 5 + 1], u2 = wr[dh * 5 + 2];
      float u3 = wr[dh * 5 + 3], u4 = wr[dh * 5 + 4];
      a0 += v0 * u0 + v1 * u1 + v2 * u2 + v3 * u3 + v4 * u4;
      a1 += v1 * u0 + v2 * u1 + v3 * u2 + v4 * u3 + v5 * u4;
      a2 += v2 * u0 + v3 * u1 + v4 * u2 + v5 * u3 + v6 * u4;
      a3 += v3 * u0 + v4 * u1 + v5 * u2 + v6 * u3 + v7 * u4;
    }
    size_t base = (size_t)bc * HW_ + h * W_ + w4;
    ushort4 pk = make_ushort4(f2bf_bits(a0), f2bf_bits(a1), f2bf_bits(a2), f2bf_bits(a3));
    *reinterpret_cast<ushort4*>(reinterpret_cast<unsigned short*>(z) + base) = pk;
  }
}

// ---------------- K3b: channel LN over z -> yT (bf16, [j][c]); coalesced via LDS transpose ----------------
__global__ __launch_bounds__(256) void ln_kernel(const bf16* __restrict__ z,
                                                 const float* __restrict__ ln2_w,
                                                 const float* __restrict__ ln2_b,
                                                 bf16* __restrict__ yT) {
  int hw0 = blockIdx.x * 64;
  int b = blockIdx.y;
  int tid = threadIdx.x;
  int wq = tid & 63;
  int cq = tid >> 6;
  __shared__ unsigned short zt[C_][64];
  __shared__ unsigned short yt[64][136];
  __shared__ float redS[4][64];
  __shared__ float redQ[4][64];
  __shared__ float meanArr[64];
  __shared__ float invArr[64];
  float s = 0.f, q = 0.f;
  const unsigned short* zp = reinterpret_cast<const unsigned short*>(z);
#pragma unroll 4
  for (int k = 0; k < 32; ++k) {
    int c = cq * 32 + k;
    unsigned short u = zp[((size_t)(b * C_ + c)) * HW_ + hw0 + wq];
    float v = bf2f(u);
    s += v;
    q += v * v;
    zt[c][wq] = u;
  }
  redS[cq][wq] = s;
  redQ[cq][wq] = q;
  __syncthreads();
  if (cq == 0) {
    float ss = redS[0][wq] + redS[1][wq] + redS[2][wq] + redS[3][wq];
    float qq = redQ[0][wq] + redQ[1][wq] + redQ[2][wq] + redQ[3][wq];
    float m = ss * (1.0f / C_);
    float var = qq * (1.0f / C_) - m * m;
    meanArr[wq] = m;
    invArr[wq] = rsqrtf(fmaxf(var, 0.f) + EPS_);
  }
  __syncthreads();
  float m = meanArr[wq], iv = invArr[wq];
#pragma unroll
  for (int g = 0; g < 4; ++g) {
    unsigned short pk[8];
#pragma unroll
    for (int i = 0; i < 8; ++i) {
      int c = cq * 32 + g * 8 + i;
      float v = bf2f(zt[c][wq]);
      pk[i] = f2bf_bits((v - m) * iv * ln2_w[c] + ln2_b[c]);
    }
    int4 t;
    __builtin_memcpy(&t, pk, 16);
    *reinterpret_cast<int4*>(&yt[wq][cq * 32 + g * 8]) = t;
  }
  __syncthreads();
  unsigned short* yp = reinterpret_cast<unsigned short*>(yT);
#pragma unroll
  for (int i = 0; i < 4; ++i) {
    int t = tid + 256 * i;
    int row = t >> 4, ch = t & 15;
    int4 v = *reinterpret_cast<const int4*>(&yt[row][ch * 8]);
    *reinterpret_cast<int4*>(yp + ((size_t)(b * HW_ + hw0 + row)) * C_ + ch * 8) = v;
  }
}

// ---------------- K4: expand MFMA GEMM + GELU + gx2 ----------------
// 128j x 64o tile, 4 waves 2x2 (wave tile 64x32, acc=32 regs), 6 blocks/CU target
__global__ __launch_bounds__(256, 6) void expand_mfma(const bf16* __restrict__ yT,
                                                      const bf16* __restrict__ weB,
                                                      bf16* __restrict__ eT,
                                                      float* __restrict__ gx2) {
  int j0 = blockIdx.x * 128;
  int o0 = blockIdx.y * 64;
  int tid = threadIdx.x;
  int lane = tid & 63, wid = tid >> 6;
  int wm = wid >> 1, wn = wid & 1;
  int quad = lane >> 4, l15 = lane & 15;
  __shared__ short As[128][40];   // 10,240 B
  __shared__ short Bs[64][40];    //  5,120 B
  f32x4 acc[4][2] = {};
  const short* yTs = reinterpret_cast<const short*>(yT);
  const short* weS = reinterpret_cast<const short*>(weB);
  for (int k0 = 0; k0 < C_; k0 += 32) {
#pragma unroll
    for (int t = tid; t < 512; t += 256) {
      int r = t >> 2, ch = t & 3;
      int4 va = *reinterpret_cast<const int4*>(yTs + (size_t)(j0 + r) * C_ + k0 + ch * 8);
      *reinterpret_cast<int4*>(&As[r][ch * 8]) = va;
    }
    {
      int r = tid >> 2, ch = tid & 3;
      int4 vb = *reinterpret_cast<const int4*>(weS + (size_t)(o0 + r) * C_ + k0 + ch * 8);
      *reinterpret_cast<int4*>(&Bs[r][ch * 8]) = vb;
    }
    __syncthreads();
    short8 a[4], bfr[2];
#pragma unroll
    for (int mf = 0; mf < 4; ++mf)
      a[mf] = *reinterpret_cast<const short8*>(&As[wm * 64 + mf * 16 + l15][quad * 8]);
#pragma unroll
    for (int nf = 0; nf < 2; ++nf)
      bfr[nf] = *reinterpret_cast<const short8*>(&Bs[wn * 32 + nf * 16 + l15][quad * 8]);
#pragma unroll
    for (int mf = 0; mf < 4; ++mf)
#pragma unroll
      for (int nf = 0; nf < 2; ++nf)
        acc[mf][nf] = __builtin_amdgcn_mfma_f32_16x16x32_bf16(a[mf], bfr[nf], acc[mf][nf], 0, 0, 0);
    __syncthreads();
  }
  unsigned short* eP = reinterpret_cast<unsigned short*>(eT);
#pragma unroll
  for (int mf = 0; mf < 4; ++mf) {
    int jm = j0 + wm * 64 + mf * 16;     // 16-aligned -> single b per m-frag
    int bb = jm / HW_;
    int jb = jm + quad * 4;
#pragma unroll
    for (int nf = 0; nf < 2; ++nf) {
      int o = o0 + wn * 32 + nf * 16 + l15;
      float g2 = 0.f;
#pragma unroll
      for (int r = 0; r < 4; ++r) {
        float ge = fast_gelu(acc[mf][nf][r]);
        g2 += ge * ge;
        eP[(size_t)(jb + r) * CE_ + o] = f2bf_bits(ge);
      }
      g2 += __shfl_xor(g2, 16, 64);
      g2 += __shfl_xor(g2, 32, 64);
      if (quad == 0) atomicAdd(&gx2[bb * CE_ + o], g2);
    }
  }
}

// ---------------- K5a: GRN per-batch scale ----------------
__global__ __launch_bounds__(512) void grn_scale_kernel(const float* __restrict__ gx2,
                                                        const float* __restrict__ gamma,
                                                        float* __restrict__ scale) {
  int b = blockIdx.x;
  int o = threadIdx.x;
  float gx = sqrtf(gx2[b * CE_ + o]);
  float s = wave_reduce_sum(gx);
  __shared__ float red[8];
  __shared__ float meansh;
  int lane = o & 63, wid = o >> 6;
  if (lane == 0) red[wid] = s;
  __syncthreads();
  if (o == 0) {
    float t = 0.f;
    for (int i = 0; i < 8; ++i) t += red[i];
    meansh = t * (1.0f / CE_);
  }
  __syncthreads();
  scale[b * CE_ + o] = 1.0f + gamma[o] * (gx / (meansh + EPS_));
}

// ---------------- K5b: sb[c] = sum_o w_shrink[c,o] * beta[o] ----------------
__global__ __launch_bounds__(128) void sb_kernel(const float* __restrict__ w_shrink,
                                                 const float* __restrict__ beta,
                                                 float* __restrict__ sb) {
  int c = threadIdx.x;
  float acc = 0.f;
  for (int o = 0; o < CE_; ++o) acc += w_shrink[c * CE_ + o] * beta[o];
  sb[c] = acc;
}

// ---------------- K5c: sws[b][c][o] = ws[c][o] * scale[b][o] (bf16) ----------------
__global__ __launch_bounds__(256) void scale_ws_kernel(const float* __restrict__ ws,
                                                       const float* __restrict__ scale,
                                                       bf16* __restrict__ sws) {
  int c = blockIdx.x;
  int b = blockIdx.y;
  const float* sp = scale + b * CE_;
  const float* wp = ws + (size_t)c * CE_;
  bf16* op = sws + ((size_t)(b * C_ + c)) * CE_;
  for (int i = threadIdx.x; i < CE_; i += 256)
    op[i] = __float2bfloat16(wp[i] * sp[i]);
}

// ---------------- K6: shrink MFMA GEMM + bias + residual ----------------
// 512 threads, 8 waves (2 hw x 4 c), wave tile 64x32 (acc=32 regs), 3 blocks/CU target
__global__ __launch_bounds__(512, 6) void shrink_mfma(const bf16* __restrict__ eT,
                                                      const bf16* __restrict__ sws,
                                                      const float* __restrict__ sb,
                                                      const float* __restrict__ x,
                                                      float* __restrict__ out) {
  int hw0 = blockIdx.x * 128;   // last tile: rows 64..127 invalid
  int b = blockIdx.y;
  int tid = threadIdx.x;
  int lane = tid & 63, wid = tid >> 6;
  int wm = wid >> 2;            // hw half (0..1)
  int wn = wid & 3;             // c quarter (0..3)
  int quad = lane >> 4, l15 = lane & 15;
  __shared__ short As[128][40];   // [hw][o-chunk]
  __shared__ short Bs[128][40];   // [c][o-chunk]
  f32x4 acc[4][2] = {};
  const short* eS = reinterpret_cast<const short*>(eT) + (size_t)b * HW_ * CE_;
  const short* wsS = reinterpret_cast<const short*>(sws) + (size_t)b * C_ * CE_;
  for (int k0 = 0; k0 < CE_; k0 += 32) {
    {
      int r = tid >> 2, ch = tid & 3;
      int hwc = hw0 + r; if (hwc >= HW_) hwc = HW_ - 1;  // clamp, masked at store
      int4 va = *reinterpret_cast<const int4*>(eS + (size_t)hwc * CE_ + k0 + ch * 8);
      *reinterpret_cast<int4*>(&As[r][ch * 8]) = va;
      int4 vb = *reinterpret_cast<const int4*>(wsS + (size_t)r * CE_ + k0 + ch * 8);
      *reinterpret_cast<int4*>(&Bs[r][ch * 8]) = vb;
    }
    __syncthreads();
    short8 a[4], bfr[2];
#pragma unroll
    for (int mf = 0; mf < 4; ++mf)
      a[mf] = *reinterpret_cast<const short8*>(&As[wm * 64 + mf * 16 + l15][quad * 8]);
#pragma unroll
    for (int nf = 0; nf < 2; ++nf)
      bfr[nf] = *reinterpret_cast<const short8*>(&Bs[wn * 32 + nf * 16 + l15][quad * 8]);
#pragma unroll
    for (int mf = 0; mf < 4; ++mf)
#pragma unroll
      for (int nf = 0; nf < 2; ++nf)
        acc[mf][nf] = __builtin_amdgcn_mfma_f32_16x16x32_bf16(a[mf], bfr[nf], acc[mf][nf], 0, 0, 0);
    __syncthreads();
  }
#pragma unroll
  for (int mf = 0; mf < 4; ++mf) {
    int hw = hw0 + wm * 64 + mf * 16 + quad * 4;
    if (hw < HW_) {
#pragma unroll
      for (int nf = 0; nf < 2; ++nf) {
        int c = wn * 32 + nf * 16 + l15;
        size_t base = ((size_t)(b * C_ + c)) * HW_ + hw;
        float add = sb[c];
        float4 xv = *reinterpret_cast<const float4*>(x + base);
        float4 ov;
        ov.x = acc[mf][nf][0] + add + xv.x;
        ov.y = acc[mf][nf][1] + add + xv.y;
        ov.z = acc[mf][nf][2] + add + xv.z;
        ov.w = acc[mf][nf][3] + add + xv.w;
        *reinterpret_cast<float4*>(out + base) = ov;
      }
    }
  }
}

extern "C" void kernel_launch(void* const* d_in, const int* in_sizes, int n_in,
                              void* d_out, int out_size, void* d_ws, size_t ws_size,
                              hipStream_t stream) {
  (void)in_sizes; (void)n_in; (void)out_size; (void)ws_size;
  const float* x        = (const float*)d_in[0];
  const float* w_fc1    = (const float*)d_in[1];
  const float* ln1_w    = (const float*)d_in[2];
  const float* ln1_b    = (const float*)d_in[3];
  const float* w_fc2    = (const float*)d_in[4];
  const float* ln2_w    = (const float*)d_in[5];
  const float* ln2_b    = (const float*)d_in[6];
  const float* w_expand = (const float*)d_in[7];
  const float* w_shrink = (const float*)d_in[8];
  const float* gamma    = (const float*)d_in[9];
  const float* beta     = (const float*)d_in[10];
  float* out = (float*)d_out;

  char* ws = (char*)d_ws;
  float* pooled = (float*)(ws + 0);
  float* dyn    = (float*)(ws + 16384);
  float* gx2    = (float*)(ws + 425984);
  float* scale  = (float*)(ws + 491520);
  float* sb     = (float*)(ws + 557056);
  bf16*  weB    = (bf16*)(ws + 557568);
  bf16*  yT     = (bf16*)(ws + 819712);
  bf16*  sws    = (bf16*)(ws + 819712);   // alias: yT dead after expand_mfma
  bf16*  eT     = (bf16*)(ws + 26509824);
  bf16*  z      = eT;                     // alias: z dead before expand_mfma writes eT

  prep_kernel<<<256, 256, 0, stream>>>(w_expand, weB);
  pool_kernel<<<B_ * C_, 256, 0, stream>>>(x, pooled);
  fc_kernel<<<B_, 256, 0, stream>>>(pooled, w_fc1, ln1_w, ln1_b, w_fc2, dyn);
  conv_kernel<<<B_ * C_, 256, 0, stream>>>(x, dyn, z);
  ln_kernel<<<dim3(49, B_), 256, 0, stream>>>(z, ln2_w, ln2_b, yT);
  hipMemsetAsync(gx2, 0, B_ * CE_ * sizeof(float), stream);
  expand_mfma<<<dim3(784, 8), 256, 0, stream>>>(yT, weB, eT, gx2);
  grn_scale_kernel<<<B_, 512, 0, stream>>>(gx2, gamma, scale);
  sb_kernel<<<1, 128, 0, stream>>>(w_shrink, beta, sb);
  scale_ws_kernel<<<dim3(C_, B_), 256, 0, stream>>>(w_shrink, scale, sws);
  shrink_mfma<<<dim3(25, B_), 512, 0, stream>>>(eT, sws, sb, x, out);
}